// Round 16
// baseline (130.411 us; speedup 1.0000x reference)
//
#include <hip/hip_runtime.h>
#include <hip/hip_bf16.h>
#include <cstdint>

typedef __attribute__((ext_vector_type(4))) float f32x4;
typedef __attribute__((ext_vector_type(8))) short s16x8;

#define NB   32
#define NL   2048
#define NH   512
#define NM   (NB * NL)          // 65536 rows
#define SCALE 0.04419417382415922f  // 1/sqrt(512)

__device__ __forceinline__ ushort f2bf(float f) {
    __hip_bfloat16 b = __float2bfloat16(f);   // pairs fuse into v_cvt_pk_bf16_f32
    return *reinterpret_cast<ushort*>(&b);
}
__device__ __forceinline__ float bf2f(unsigned u) {
    union { unsigned u; float f; } a; a.u = u << 16; return a.f;
}
__device__ __forceinline__ unsigned long long pack4(float4 f) {
    union { ushort u[4]; unsigned long long v; } p;
    p.u[0] = f2bf(f.x); p.u[1] = f2bf(f.y); p.u[2] = f2bf(f.z); p.u[3] = f2bf(f.w);
    return p.v;
}

// async global->LDS, 16B/lane: dest = wave-uniform base + lane*16; global addr per-lane
#define GL16(g, l)                                                         \
    __builtin_amdgcn_global_load_lds(                                      \
        (const __attribute__((address_space(1))) unsigned int*)(g),        \
        (__attribute__((address_space(3))) unsigned int*)(l), 16, 0, 0)

// ============================================================================
// k_conv: one-shot-wave conversion (max TLP, no serial chains).
//   blocks 0..32767: ref f32 -> bf16 (1 float4 / thread)
//   blocks 32768..33023: W_ref f32 -> bf16
//   blocks 33024..33055: eq[b][o] = dot(query[b,:], W_q[o,:])
// ============================================================================
__global__ __launch_bounds__(256) void k_conv(const float* __restrict__ ref,
                                              ushort* __restrict__ refb,
                                              const float* __restrict__ W,
                                              ushort* __restrict__ Wb,
                                              const float* __restrict__ query,
                                              const float* __restrict__ Wq,
                                              float* __restrict__ eq) {
    int bid = blockIdx.x;
    int t = threadIdx.x;
    if (bid < 32768) {
        int g = bid * 256 + t;                   // 8,388,608 float4
        ((unsigned long long*)refb)[g] = pack4(((const float4*)ref)[g]);
    } else if (bid < 33024) {
        int g = (bid - 32768) * 256 + t;         // 65,536 float4
        ((unsigned long long*)Wb)[g] = pack4(((const float4*)W)[g]);
    } else {
        __shared__ float q[NH];
        int b = bid - 33024;
        q[t] = query[b * NH + t];
        q[t + 256] = query[b * NH + t + 256];
        __syncthreads();
#pragma unroll
        for (int half = 0; half < 2; ++half) {
            int o = t + half * 256;
            const float4* w = (const float4*)(Wq + (size_t)o * NH);
            float acc = 0.f;
#pragma unroll 4
            for (int i = 0; i < NH / 4; ++i) {
                float4 x = w[i];
                acc += q[4 * i] * x.x + q[4 * i + 1] * x.y + q[4 * i + 2] * x.z + q[4 * i + 3] * x.w;
            }
            eq[b * NH + o] = acc;
        }
    }
}

// ============================================================================
// k_gemm8: large-sync-period GEMM (T3/T4 regime). 512 blocks x 512 thr (8 waves).
// BM=256, BN=256 (2 n-tiles, partials), BK=64, 8 K-tiles.
// Per K-tile: ONE vmcnt(8) wait (2-tile staging depth, never drained till the
// last tile) + TWO barriers; body = 24 ds_read_b128 + 64 MFMA per wave,
// compiler-scheduled (no sched_barrier). setprio around MFMA cluster.
// LDS 128 KB: 2 bufs x (A[256][64] + B[256][64]) bf16, chunk-XOR swizzle
// slot = chunk ^ (row&7), applied on the pre-swizzled gl16 GLOBAL source and
// on ds_read (both-sides involution; verified 8 lanes/4-bank group = min).
// Wave wid: wr=wid>>2 (row half), wc=wid&3 (col quarter); out 128x64.
// ============================================================================
__global__ __launch_bounds__(512, 1) void k_gemm8(const ushort* __restrict__ refb,
                                                  const ushort* __restrict__ Wb,
                                                  const float* __restrict__ eq,
                                                  const float* __restrict__ v,
                                                  float* __restrict__ part) {
    __shared__ ushort smem[65536];               // 128 KB
    ushort* As0 = smem;                          // [256][64]
    ushort* Bs0 = smem + 16384;
    ushort* As1 = smem + 32768;
    ushort* Bs1 = smem + 49152;

    int tid = threadIdx.x;
    int lane = tid & 63, wid = tid >> 6;         // 8 waves
    int wr = wid >> 2, wc = wid & 3;

    int phys = blockIdx.x;                       // 512 blocks
    int xcd = phys & 7, slot = phys >> 3;        // sibling n-tiles same XCD
    int mt = xcd * 32 + (slot >> 1);             // 256 m-tiles
    int nt = slot & 1;                           // 2 n-tiles
    int m0g = mt << 8, n0 = nt << 8;             // 256 rows / 256 cols
    int b = mt >> 3;                             // batch (8 m-tiles per batch)

    f32x4 acc[8][4];
#pragma unroll
    for (int i = 0; i < 8; ++i)
#pragma unroll
        for (int j = 0; j < 4; ++j) acc[i][j] = (f32x4)(0.f);

    int lr = lane & 15, kq = lane >> 4;
    int l7 = lr & 7;
    int sA0 = ((kq) ^ l7) << 3;                  // k-slice 0 chunk slot (ushorts)
    int sA1 = ((4 + kq) ^ l7) << 3;              // k-slice 1
    int abase0 = (wr * 128 + lr) * 64;           // + fr*1024
    int bbase0 = (wc * 64 + lr) * 64;            // + fc*1024

    // staging: per wave 8 gl16/tile (A:4, B:4), rows wid*16..+16 of each half
#define STAGE(Asb, Bsb, kt)                                                    \
    {   _Pragma("unroll")                                                      \
        for (int ho = 0; ho < 4; ++ho) {                                       \
            int br = (ho >> 1) * 128 + wid * 16 + (ho & 1) * 8;                \
            int rl = br + (lane >> 3);                                         \
            int gc = (lane & 7) ^ (rl & 7);                                    \
            GL16(refb + (size_t)(m0g + rl) * NH + (kt) * 64 + gc * 8, (Asb) + br * 64); \
            GL16(Wb   + (size_t)(n0  + rl) * NH + (kt) * 64 + gc * 8, (Bsb) + br * 64); \
        } }

#define TILE_BODY(Asb, Bsb)                                                    \
    {   s16x8 bq[4][2];                                                        \
        _Pragma("unroll")                                                      \
        for (int fc = 0; fc < 4; ++fc) {                                       \
            bq[fc][0] = *(const s16x8*)&(Bsb)[bbase0 + fc * 1024 + sA0];       \
            bq[fc][1] = *(const s16x8*)&(Bsb)[bbase0 + fc * 1024 + sA1];       \
        }                                                                      \
        __builtin_amdgcn_s_setprio(1);                                         \
        _Pragma("unroll")                                                      \
        for (int fr = 0; fr < 8; ++fr) {                                       \
            s16x8 a0 = *(const s16x8*)&(Asb)[abase0 + fr * 1024 + sA0];        \
            s16x8 a1 = *(const s16x8*)&(Asb)[abase0 + fr * 1024 + sA1];        \
            _Pragma("unroll")                                                  \
            for (int fc = 0; fc < 4; ++fc) {                                   \
                acc[fr][fc] = __builtin_amdgcn_mfma_f32_16x16x32_bf16(         \
                    a0, bq[fc][0], acc[fr][fc], 0, 0, 0);                      \
                acc[fr][fc] = __builtin_amdgcn_mfma_f32_16x16x32_bf16(         \
                    a1, bq[fc][1], acc[fr][fc], 0, 0, 0);                      \
            }                                                                  \
        }                                                                      \
        __builtin_amdgcn_s_setprio(0);                                         \
    }

#define TILE(Asb, Bsb, WAITN, DOSTAGE, Asn, Bsn, kstage)                       \
    {   asm volatile("s_waitcnt vmcnt(" #WAITN ")" ::: "memory");              \
        __builtin_amdgcn_s_barrier();                                          \
        TILE_BODY(Asb, Bsb)                                                    \
        asm volatile("s_waitcnt lgkmcnt(0)" ::: "memory");                     \
        __builtin_amdgcn_s_barrier();                                          \
        if (DOSTAGE) STAGE(Asn, Bsn, kstage)                                   \
    }

    // prologue: tiles 0,1 staged (16 wave-ops outstanding)
    STAGE(As0, Bs0, 0)
    STAGE(As1, Bs1, 1)

    // 8 K-tiles; stage kt+2 (same-parity buffer) while kt+1 is in flight
    TILE(As0, Bs0, 8, 1, As0, Bs0, 2)    // kt=0
    TILE(As1, Bs1, 8, 1, As1, Bs1, 3)    // kt=1
    TILE(As0, Bs0, 8, 1, As0, Bs0, 4)    // kt=2
    TILE(As1, Bs1, 8, 1, As1, Bs1, 5)    // kt=3
    TILE(As0, Bs0, 8, 1, As0, Bs0, 6)    // kt=4
    TILE(As1, Bs1, 8, 1, As1, Bs1, 7)    // kt=5
    TILE(As0, Bs0, 8, 0, As0, Bs0, 0)    // kt=6
    TILE(As1, Bs1, 0, 0, As1, Bs1, 0)    // kt=7

#undef STAGE
#undef TILE_BODY
#undef TILE

    __syncthreads();                             // before sc_red overlay

    // ---- epilogue: partial v-dot over this block's 256 cols ----
    float* sc_red = (float*)smem;                // [8][128]
    const float* eqb = eq + b * NH;
    float vv[4], ee[4];
#pragma unroll
    for (int fc = 0; fc < 4; ++fc) {
        int c = n0 + wc * 64 + fc * 16 + lr;
        vv[fc] = v[c];
        ee[fc] = eqb[c];
    }
#pragma unroll
    for (int fr = 0; fr < 8; ++fr) {
#pragma unroll
        for (int reg = 0; reg < 4; ++reg) {
            float s = 0.f;
#pragma unroll
            for (int fc = 0; fc < 4; ++fc) {
                float x = acc[fr][fc][reg] + ee[fc];
                float t = 1.f - 2.f / (__expf(2.f * x) + 1.f);  // tanh
                s += vv[fc] * t;
            }
            s += __shfl_xor(s, 1);
            s += __shfl_xor(s, 2);
            s += __shfl_xor(s, 4);
            s += __shfl_xor(s, 8);
            if (lr == 0) sc_red[wid * 128 + fr * 16 + kq * 4 + reg] = s;
        }
    }
    __syncthreads();
    if (tid < 256) {
        int row = tid;
        int g0 = (row >> 7) * 4;                 // waves 0-3 -> rows 0-127, 4-7 -> 128-255
        int rl = row & 127;
        float s = sc_red[(g0 + 0) * 128 + rl] + sc_red[(g0 + 1) * 128 + rl]
                + sc_red[(g0 + 2) * 128 + rl] + sc_red[(g0 + 3) * 128 + rl];
        part[(size_t)nt * NM + m0g + row] = s;
    }
}

// ============================================================================
// k_smglp: combine nt-partials + mask -> scores; softmax; glimpse slice (bf16).
// grid (16 sp, 32 b). sp==0 writes out_sc.
// ============================================================================
__global__ __launch_bounds__(256) void k_smglp(const float* __restrict__ part,
                                               const int* __restrict__ mask,
                                               const ushort* __restrict__ refb,
                                               float* __restrict__ out_sc,
                                               float* __restrict__ glp) {
    int sp = blockIdx.x, b = blockIdx.y;
    int tid = threadIdx.x;
    int lane = tid & 63, wid = tid >> 6;
    __shared__ float red[4];
    __shared__ float asl[128];    // unnormalized exp for rows sp*128..+128
    float sc[8];
    float mx = -3.4e38f;
#pragma unroll
    for (int i = 0; i < 8; ++i) {
        int m = b * NL + i * 256 + tid;
        float s = (part[m] + part[NM + m]) * SCALE;
        if (mask[m] != 0) s = -1e9f;
        if (sp == 0) out_sc[m] = s;
        sc[i] = s;
        mx = fmaxf(mx, s);
    }
#pragma unroll
    for (int o = 32; o >= 1; o >>= 1) mx = fmaxf(mx, __shfl_xor(mx, o));
    if (lane == 0) red[wid] = mx;
    __syncthreads();
    mx = fmaxf(fmaxf(red[0], red[1]), fmaxf(red[2], red[3]));
    __syncthreads();
    float ls = 0.f;
#pragma unroll
    for (int i = 0; i < 8; ++i) {
        float e = __expf(sc[i] - mx);
        ls += e;
        if (i == (sp >> 1) && (tid >> 7) == (sp & 1)) asl[tid & 127] = e;
    }
#pragma unroll
    for (int o = 32; o >= 1; o >>= 1) ls += __shfl_xor(ls, o);
    if (lane == 0) red[wid] = ls;
    __syncthreads();
    float inv = 1.f / (red[0] + red[1] + red[2] + red[3]);

    const ushort* rb = refb + ((size_t)b * NL + sp * 128) * NH;
    float2 acc = make_float2(0.f, 0.f);
#pragma unroll 4
    for (int l = 0; l < 128; ++l) {
        float a = asl[l];
        unsigned r = ((const unsigned*)(rb + (size_t)l * NH))[tid];
        acc.x += a * bf2f(r & 0xFFFFu);
        acc.y += a * bf2f(r >> 16);
    }
    acc.x *= inv;
    acc.y *= inv;
    ((float2*)(glp + (size_t)(sp * NB + b) * NH))[tid] = acc;
}

// ---- reduce glimpse partials (16 splits) ----
__global__ __launch_bounds__(256) void k_gred(const float* __restrict__ glp,
                                              float* __restrict__ out_gl) {
    int idx = blockIdx.x * 256 + threadIdx.x;   // 16384 = B*H
    float s = 0.f;
#pragma unroll
    for (int sp = 0; sp < 16; ++sp) s += glp[sp * (NB * NH) + idx];
    out_gl[idx] = s;
}

extern "C" void kernel_launch(void* const* d_in, const int* in_sizes, int n_in,
                              void* d_out, int out_size, void* d_ws, size_t ws_size,
                              hipStream_t stream) {
    const float* query = (const float*)d_in[0];
    const float* ref   = (const float*)d_in[1];
    const int*   mask  = (const int*)d_in[2];
    const float* W_ref = (const float*)d_in[3];
    const float* W_q   = (const float*)d_in[4];
    const float* v     = (const float*)d_in[5];

    float* out_gl = (float*)d_out;              // 32*512
    float* out_sc = out_gl + NB * NH;           // 32*2048 (final scores)

    char* w = (char*)d_ws;
    ushort* wW   = (ushort*)w;                  // 524,288 B @ 0
    float*  eq   = (float*)(w + 524288);        // 65,536 B
    ushort* refb = (ushort*)(w + 589824);       // 67,108,864 B
    float*  part = (float*)(w + 589824 + 67108864);            // 524,288 B
    float*  glp  = (float*)(w + 589824 + 67108864 + 524288);   // 1,048,576 B

    k_conv<<<33056, 256, 0, stream>>>(ref, refb, W_ref, wW, query, W_q, eq);
    k_gemm8<<<512, 512, 0, stream>>>(refb, wW, eq, v, part);
    k_smglp<<<dim3(16, NB), 256, 0, stream>>>(part, mask, refb, out_sc, glp);
    k_gred<<<64, 256, 0, stream>>>(glp, out_gl);
}

// Round 17
// 130.119 us; speedup vs baseline: 1.0022x; 1.0022x over previous
//
#include <hip/hip_runtime.h>
#include <hip/hip_bf16.h>
#include <cstdint>

typedef __attribute__((ext_vector_type(4))) float f32x4;
typedef __attribute__((ext_vector_type(8))) short s16x8;

#define NB   32
#define NL   2048
#define NH   512
#define NM   (NB * NL)          // 65536 rows
#define SCALE 0.04419417382415922f  // 1/sqrt(512)

__device__ __forceinline__ ushort f2bf(float f) {
    __hip_bfloat16 b = __float2bfloat16(f);   // pairs fuse into v_cvt_pk_bf16_f32
    return *reinterpret_cast<ushort*>(&b);
}
__device__ __forceinline__ float bf2f(unsigned u) {
    union { unsigned u; float f; } a; a.u = u << 16; return a.f;
}
__device__ __forceinline__ unsigned long long pack4(float4 f) {
    union { ushort u[4]; unsigned long long v; } p;
    p.u[0] = f2bf(f.x); p.u[1] = f2bf(f.y); p.u[2] = f2bf(f.z); p.u[3] = f2bf(f.w);
    return p.v;
}

// async global->LDS, 16B/lane: dest = wave-uniform base + lane*16; global addr per-lane
#define GL16(g, l)                                                         \
    __builtin_amdgcn_global_load_lds(                                      \
        (const __attribute__((address_space(1))) unsigned int*)(g),        \
        (__attribute__((address_space(3))) unsigned int*)(l), 16, 0, 0)

// ============================================================================
// k_conv v2: long-lived streaming conversion with FORCED load batching.
// 8-load batch -> sched_barrier(0) -> 8 stores (fence prevents the compiler's
// liveness-minimizing load/store interleave that collapsed R6/R7/R16 to
// VGPR~20 serial chains at 1.5 TB/s).
//   blocks 0..2047:   ref f32 -> bf16 (16 float4/thread, 2 batches of 8)
//   blocks 2048..2063: W_ref f32 -> bf16
//   blocks 2064..2095: eq[b][o] = dot(query[b,:], W_q[o,:])
// ============================================================================
__global__ __launch_bounds__(256) void k_conv(const float* __restrict__ ref,
                                              ushort* __restrict__ refb,
                                              const float* __restrict__ W,
                                              ushort* __restrict__ Wb,
                                              const float* __restrict__ query,
                                              const float* __restrict__ Wq,
                                              float* __restrict__ eq) {
    int bid = blockIdx.x;
    int t = threadIdx.x;
    if (bid < 2064) {
        const float4* F;
        unsigned long long* U;
        size_t base;
        if (bid < 2048) {
            F = (const float4*)ref;
            U = (unsigned long long*)refb;
            base = (size_t)bid * 4096 + t;       // 2048*256*16 = 8,388,608 float4
        } else {
            F = (const float4*)W;
            U = (unsigned long long*)Wb;
            base = (size_t)(bid - 2048) * 4096 + t;  // 16*256*16 = 65,536 float4
        }
#pragma unroll
        for (int half = 0; half < 2; ++half) {
            size_t o = base + half * 2048;
            float4 f0 = F[o];
            float4 f1 = F[o + 256];
            float4 f2 = F[o + 512];
            float4 f3 = F[o + 768];
            float4 f4 = F[o + 1024];
            float4 f5 = F[o + 1280];
            float4 f6 = F[o + 1536];
            float4 f7 = F[o + 1792];
            __builtin_amdgcn_sched_barrier(0);   // all 8 loads issue first
            U[o]        = pack4(f0);
            U[o + 256]  = pack4(f1);
            U[o + 512]  = pack4(f2);
            U[o + 768]  = pack4(f3);
            U[o + 1024] = pack4(f4);
            U[o + 1280] = pack4(f5);
            U[o + 1536] = pack4(f6);
            U[o + 1792] = pack4(f7);
        }
    } else {
        __shared__ float q[NH];
        int b = bid - 2064;
        q[t] = query[b * NH + t];
        q[t + 256] = query[b * NH + t + 256];
        __syncthreads();
#pragma unroll
        for (int half = 0; half < 2; ++half) {
            int o = t + half * 256;
            const float4* w = (const float4*)(Wq + (size_t)o * NH);
            float acc = 0.f;
#pragma unroll 4
            for (int i = 0; i < NH / 4; ++i) {
                float4 x = w[i];
                acc += q[4 * i] * x.x + q[4 * i + 1] * x.y + q[4 * i + 2] * x.z + q[4 * i + 3] * x.w;
            }
            eq[b * NH + o] = acc;
        }
    }
}

// ============================================================================
// k_gemm8: large-sync-period GEMM (T3/T4 regime). 512 blocks x 512 thr (8 waves).
// BM=256, BN=256 (2 n-tiles, partials), BK=64, 8 K-tiles.  [UNCHANGED from R16:
// inferred 16-25 us -- near the 13.5 us MFMA floor.]
// ============================================================================
__global__ __launch_bounds__(512, 1) void k_gemm8(const ushort* __restrict__ refb,
                                                  const ushort* __restrict__ Wb,
                                                  const float* __restrict__ eq,
                                                  const float* __restrict__ v,
                                                  float* __restrict__ part) {
    __shared__ ushort smem[65536];               // 128 KB
    ushort* As0 = smem;                          // [256][64]
    ushort* Bs0 = smem + 16384;
    ushort* As1 = smem + 32768;
    ushort* Bs1 = smem + 49152;

    int tid = threadIdx.x;
    int lane = tid & 63, wid = tid >> 6;         // 8 waves
    int wr = wid >> 2, wc = wid & 3;

    int phys = blockIdx.x;                       // 512 blocks
    int xcd = phys & 7, slot = phys >> 3;        // sibling n-tiles same XCD
    int mt = xcd * 32 + (slot >> 1);             // 256 m-tiles
    int nt = slot & 1;                           // 2 n-tiles
    int m0g = mt << 8, n0 = nt << 8;             // 256 rows / 256 cols
    int b = mt >> 3;                             // batch (8 m-tiles per batch)

    f32x4 acc[8][4];
#pragma unroll
    for (int i = 0; i < 8; ++i)
#pragma unroll
        for (int j = 0; j < 4; ++j) acc[i][j] = (f32x4)(0.f);

    int lr = lane & 15, kq = lane >> 4;
    int l7 = lr & 7;
    int sA0 = ((kq) ^ l7) << 3;                  // k-slice 0 chunk slot (ushorts)
    int sA1 = ((4 + kq) ^ l7) << 3;              // k-slice 1
    int abase0 = (wr * 128 + lr) * 64;           // + fr*1024
    int bbase0 = (wc * 64 + lr) * 64;            // + fc*1024

#define STAGE(Asb, Bsb, kt)                                                    \
    {   _Pragma("unroll")                                                      \
        for (int ho = 0; ho < 4; ++ho) {                                       \
            int br = (ho >> 1) * 128 + wid * 16 + (ho & 1) * 8;                \
            int rl = br + (lane >> 3);                                         \
            int gc = (lane & 7) ^ (rl & 7);                                    \
            GL16(refb + (size_t)(m0g + rl) * NH + (kt) * 64 + gc * 8, (Asb) + br * 64); \
            GL16(Wb   + (size_t)(n0  + rl) * NH + (kt) * 64 + gc * 8, (Bsb) + br * 64); \
        } }

#define TILE_BODY(Asb, Bsb)                                                    \
    {   s16x8 bq[4][2];                                                        \
        _Pragma("unroll")                                                      \
        for (int fc = 0; fc < 4; ++fc) {                                       \
            bq[fc][0] = *(const s16x8*)&(Bsb)[bbase0 + fc * 1024 + sA0];       \
            bq[fc][1] = *(const s16x8*)&(Bsb)[bbase0 + fc * 1024 + sA1];       \
        }                                                                      \
        __builtin_amdgcn_s_setprio(1);                                         \
        _Pragma("unroll")                                                      \
        for (int fr = 0; fr < 8; ++fr) {                                       \
            s16x8 a0 = *(const s16x8*)&(Asb)[abase0 + fr * 1024 + sA0];        \
            s16x8 a1 = *(const s16x8*)&(Asb)[abase0 + fr * 1024 + sA1];        \
            _Pragma("unroll")                                                  \
            for (int fc = 0; fc < 4; ++fc) {                                   \
                acc[fr][fc] = __builtin_amdgcn_mfma_f32_16x16x32_bf16(         \
                    a0, bq[fc][0], acc[fr][fc], 0, 0, 0);                      \
                acc[fr][fc] = __builtin_amdgcn_mfma_f32_16x16x32_bf16(         \
                    a1, bq[fc][1], acc[fr][fc], 0, 0, 0);                      \
            }                                                                  \
        }                                                                      \
        __builtin_amdgcn_s_setprio(0);                                         \
    }

#define TILE(Asb, Bsb, WAITN, DOSTAGE, Asn, Bsn, kstage)                       \
    {   asm volatile("s_waitcnt vmcnt(" #WAITN ")" ::: "memory");              \
        __builtin_amdgcn_s_barrier();                                          \
        TILE_BODY(Asb, Bsb)                                                    \
        asm volatile("s_waitcnt lgkmcnt(0)" ::: "memory");                     \
        __builtin_amdgcn_s_barrier();                                          \
        if (DOSTAGE) STAGE(Asn, Bsn, kstage)                                   \
    }

    STAGE(As0, Bs0, 0)
    STAGE(As1, Bs1, 1)

    TILE(As0, Bs0, 8, 1, As0, Bs0, 2)    // kt=0
    TILE(As1, Bs1, 8, 1, As1, Bs1, 3)    // kt=1
    TILE(As0, Bs0, 8, 1, As0, Bs0, 4)    // kt=2
    TILE(As1, Bs1, 8, 1, As1, Bs1, 5)    // kt=3
    TILE(As0, Bs0, 8, 1, As0, Bs0, 6)    // kt=4
    TILE(As1, Bs1, 8, 1, As1, Bs1, 7)    // kt=5
    TILE(As0, Bs0, 8, 0, As0, Bs0, 0)    // kt=6
    TILE(As1, Bs1, 0, 0, As1, Bs1, 0)    // kt=7

#undef STAGE
#undef TILE_BODY
#undef TILE

    __syncthreads();                             // before sc_red overlay

    // ---- epilogue: partial v-dot over this block's 256 cols ----
    float* sc_red = (float*)smem;                // [8][128]
    const float* eqb = eq + b * NH;
    float vv[4], ee[4];
#pragma unroll
    for (int fc = 0; fc < 4; ++fc) {
        int c = n0 + wc * 64 + fc * 16 + lr;
        vv[fc] = v[c];
        ee[fc] = eqb[c];
    }
#pragma unroll
    for (int fr = 0; fr < 8; ++fr) {
#pragma unroll
        for (int reg = 0; reg < 4; ++reg) {
            float s = 0.f;
#pragma unroll
            for (int fc = 0; fc < 4; ++fc) {
                float x = acc[fr][fc][reg] + ee[fc];
                float t = 1.f - 2.f / (__expf(2.f * x) + 1.f);  // tanh
                s += vv[fc] * t;
            }
            s += __shfl_xor(s, 1);
            s += __shfl_xor(s, 2);
            s += __shfl_xor(s, 4);
            s += __shfl_xor(s, 8);
            if (lr == 0) sc_red[wid * 128 + fr * 16 + kq * 4 + reg] = s;
        }
    }
    __syncthreads();
    if (tid < 256) {
        int row = tid;
        int g0 = (row >> 7) * 4;                 // waves 0-3 -> rows 0-127, 4-7 -> 128-255
        int rl = row & 127;
        float s = sc_red[(g0 + 0) * 128 + rl] + sc_red[(g0 + 1) * 128 + rl]
                + sc_red[(g0 + 2) * 128 + rl] + sc_red[(g0 + 3) * 128 + rl];
        part[(size_t)nt * NM + m0g + row] = s;
    }
}

// ============================================================================
// k_smglp: combine nt-partials + mask -> scores; softmax; glimpse slice (bf16).
// grid (16 sp, 32 b). sp==0 writes out_sc.
// ============================================================================
__global__ __launch_bounds__(256) void k_smglp(const float* __restrict__ part,
                                               const int* __restrict__ mask,
                                               const ushort* __restrict__ refb,
                                               float* __restrict__ out_sc,
                                               float* __restrict__ glp) {
    int sp = blockIdx.x, b = blockIdx.y;
    int tid = threadIdx.x;
    int lane = tid & 63, wid = tid >> 6;
    __shared__ float red[4];
    __shared__ float asl[128];    // unnormalized exp for rows sp*128..+128
    float sc[8];
    float mx = -3.4e38f;
#pragma unroll
    for (int i = 0; i < 8; ++i) {
        int m = b * NL + i * 256 + tid;
        float s = (part[m] + part[NM + m]) * SCALE;
        if (mask[m] != 0) s = -1e9f;
        if (sp == 0) out_sc[m] = s;
        sc[i] = s;
        mx = fmaxf(mx, s);
    }
#pragma unroll
    for (int o = 32; o >= 1; o >>= 1) mx = fmaxf(mx, __shfl_xor(mx, o));
    if (lane == 0) red[wid] = mx;
    __syncthreads();
    mx = fmaxf(fmaxf(red[0], red[1]), fmaxf(red[2], red[3]));
    __syncthreads();
    float ls = 0.f;
#pragma unroll
    for (int i = 0; i < 8; ++i) {
        float e = __expf(sc[i] - mx);
        ls += e;
        if (i == (sp >> 1) && (tid >> 7) == (sp & 1)) asl[tid & 127] = e;
    }
#pragma unroll
    for (int o = 32; o >= 1; o >>= 1) ls += __shfl_xor(ls, o);
    if (lane == 0) red[wid] = ls;
    __syncthreads();
    float inv = 1.f / (red[0] + red[1] + red[2] + red[3]);

    const ushort* rb = refb + ((size_t)b * NL + sp * 128) * NH;
    float2 acc = make_float2(0.f, 0.f);
#pragma unroll 4
    for (int l = 0; l < 128; ++l) {
        float a = asl[l];
        unsigned r = ((const unsigned*)(rb + (size_t)l * NH))[tid];
        acc.x += a * bf2f(r & 0xFFFFu);
        acc.y += a * bf2f(r >> 16);
    }
    acc.x *= inv;
    acc.y *= inv;
    ((float2*)(glp + (size_t)(sp * NB + b) * NH))[tid] = acc;
}

// ---- reduce glimpse partials (16 splits) ----
__global__ __launch_bounds__(256) void k_gred(const float* __restrict__ glp,
                                              float* __restrict__ out_gl) {
    int idx = blockIdx.x * 256 + threadIdx.x;   // 16384 = B*H
    float s = 0.f;
#pragma unroll
    for (int sp = 0; sp < 16; ++sp) s += glp[sp * (NB * NH) + idx];
    out_gl[idx] = s;
}

extern "C" void kernel_launch(void* const* d_in, const int* in_sizes, int n_in,
                              void* d_out, int out_size, void* d_ws, size_t ws_size,
                              hipStream_t stream) {
    const float* query = (const float*)d_in[0];
    const float* ref   = (const float*)d_in[1];
    const int*   mask  = (const int*)d_in[2];
    const float* W_ref = (const float*)d_in[3];
    const float* W_q   = (const float*)d_in[4];
    const float* v     = (const float*)d_in[5];

    float* out_gl = (float*)d_out;              // 32*512
    float* out_sc = out_gl + NB * NH;           // 32*2048 (final scores)

    char* w = (char*)d_ws;
    ushort* wW   = (ushort*)w;                  // 524,288 B @ 0
    float*  eq   = (float*)(w + 524288);        // 65,536 B
    ushort* refb = (ushort*)(w + 589824);       // 67,108,864 B
    float*  part = (float*)(w + 589824 + 67108864);            // 524,288 B
    float*  glp  = (float*)(w + 589824 + 67108864 + 524288);   // 1,048,576 B

    k_conv<<<2096, 256, 0, stream>>>(ref, refb, W_ref, wW, query, W_q, eq);
    k_gemm8<<<512, 512, 0, stream>>>(refb, wW, eq, v, part);
    k_smglp<<<dim3(16, NB), 256, 0, stream>>>(part, mask, refb, out_sc, glp);
    k_gred<<<64, 256, 0, stream>>>(glp, out_gl);
}